// Round 14
// baseline (369.717 us; speedup 1.0000x reference)
//
#include <hip/hip_runtime.h>
#include <hip/hip_bf16.h>

constexpr int D = 256;   // dim_h
constexpr int PG = 1024; // nodes per graph
constexpr int BSLOT = 64; // bucket capacity per node (Poisson(8) => never hit)

typedef __attribute__((ext_vector_type(8))) short bf16x8;  // 8 bf16 in 4 VGPRs
typedef __attribute__((ext_vector_type(4))) float f32x4;

__device__ inline short f2bf(float f) {
    __hip_bfloat16 h = __float2bfloat16(f);
    return *reinterpret_cast<short*>(&h);
}
__device__ inline float bf2f(short s) {
    return __uint_as_float(((unsigned)(unsigned short)s) << 16);
}

// ===========================================================================
// prep: weights f32->bf16 (blocks 0..319) | bucket scatter (blocks 320..)
// ===========================================================================
__global__ __launch_bounds__(256) void prep_kernel(
    const float* __restrict__ w1, const float* __restrict__ w2,
    const float* __restrict__ w3, const float* __restrict__ w4,
    const float* __restrict__ w5, const float* __restrict__ w6,
    short* __restrict__ out,
    const int* __restrict__ src, const int* __restrict__ dst,
    int* __restrict__ cnt, int2* __restrict__ bucket, int E)
{
    int bid = blockIdx.x;
    if (bid >= 320) {
        int e = (bid - 320) * 256 + threadIdx.x;
        if (e < E) {
            int d = dst[e];
            int pos = atomicAdd(&cnt[d], 1);
            if (pos < BSLOT) {
                int2 v; v.x = e; v.y = src[e];
                bucket[d * BSLOT + pos] = v;
            }
        }
        return;
    }
    int i = bid * 256 + threadIdx.x;   // [0, 81920)
    const float* sp; int base;
    if (i < 16384)      { if (i < 8192) { sp = w1; base = 0; }
                          else          { sp = w2; base = 8192; } }
    else if (i < 40960) { sp = w3; base = 16384; }
    else if (i < 49152) { sp = w4; base = 40960; }
    else if (i < 65536) { sp = w5; base = 49152; }
    else                { sp = w6; base = 65536; }
    int k = i - base;
    float4 a = ((const float4*)sp)[k * 2];
    float4 b = ((const float4*)sp)[k * 2 + 1];
    bf16x8 v;
    v[0] = f2bf(a.x); v[1] = f2bf(a.y); v[2] = f2bf(a.z); v[3] = f2bf(a.w);
    v[4] = f2bf(b.x); v[5] = f2bf(b.y); v[6] = f2bf(b.z); v[7] = f2bf(b.w);
    ((bf16x8*)out)[i] = v;
}

// ===========================================================================
// bucket aggregation -> bf16 Z, also emits xb = bf16(x). One wave per node.
// ===========================================================================
__global__ __launch_bounds__(256) void csr_aggr(
    const float* __restrict__ x, const float* __restrict__ ea,
    const int* __restrict__ cnt, const int2* __restrict__ bucket,
    short* __restrict__ z, short* __restrict__ xb)
{
    int gid = blockIdx.x * 256 + threadIdx.x;
    int node = gid >> 6;
    int c = (gid & 63) << 2;
    int deg = cnt[node];
    if (deg > BSLOT) deg = BSLOT;
    const int2* bk = bucket + (size_t)node * BSLOT;
    float4 xv = *(const float4*)(x + (size_t)node * D + c);
    short4 xr;
    xr.x = f2bf(xv.x); xr.y = f2bf(xv.y); xr.z = f2bf(xv.z); xr.w = f2bf(xv.w);
    *(short4*)(xb + (size_t)node * D + c) = xr;
    float4 acc = xv;
    for (int i = 0; i < deg; ++i) {
        int2 es = bk[i];
        float4 xa = *(const float4*)(x + (size_t)es.y * D + c);
        float4 av = *(const float4*)(ea + (size_t)es.x * D + c);
        acc.x += fmaxf(xa.x + av.x, 0.f);
        acc.y += fmaxf(xa.y + av.y, 0.f);
        acc.z += fmaxf(xa.z + av.z, 0.f);
        acc.w += fmaxf(xa.w + av.w, 0.f);
    }
    short4 r;
    r.x = f2bf(acc.x); r.y = f2bf(acc.y); r.z = f2bf(acc.z); r.w = f2bf(acc.w);
    *(short4*)(z + (size_t)node * D + c) = r;
}

// ===========================================================================
// MFMA bf16 GEMM body (R7/R13-proven). SM >= 18432 shorts.
// ===========================================================================
template<bool RELU, bool ADDB, bool STATS, bool SCALEQ>
__device__ __forceinline__ void gemm_body(
    int bid, int nbx, int nwg,
    const short* __restrict__ X, const short* __restrict__ W,
    const float* __restrict__ bias, const short* __restrict__ addb,
    short* __restrict__ Y, float* __restrict__ st, int K, int M,
    short* SM)
{
    short* Xs = SM;            // 128*72
    short* Ws = SM + 9216;     // 128*72

    const int cpx = nwg >> 3;                     // nwg % 8 == 0 always
    const int wg  = (bid & 7) * cpx + (bid >> 3);
    const int r0 = (wg / nbx) * 128;
    const int c0 = (wg % nbx) * 128;

    const int t = threadIdx.x, w = t >> 6, l = t & 63;
    const int wr = w >> 1, wc = w & 1, lg = l >> 4, lm = l & 15;
    const int srow = t >> 3;            // staging row 0..31
    const int scol = (t & 7) * 8;       // staging col 0..56

    f32x4 acc[4][4];
    #pragma unroll
    for (int i = 0; i < 4; ++i)
        #pragma unroll
        for (int j = 0; j < 4; ++j)
            acc[i][j] = (f32x4){0.f, 0.f, 0.f, 0.f};

    for (int k0 = 0; k0 < K; k0 += 64) {
        __syncthreads();
        #pragma unroll
        for (int it = 0; it < 4; ++it) {
            int r = it * 32 + srow;
            bf16x8 xv = *(const bf16x8*)(X + (size_t)(r0 + r) * K + k0 + scol);
            bf16x8 wv = *(const bf16x8*)(W + (size_t)(c0 + r) * K + k0 + scol);
            *(bf16x8*)&Xs[r * 72 + scol] = xv;
            *(bf16x8*)&Ws[r * 72 + scol] = wv;
        }
        __syncthreads();

        bf16x8 af[4][2], bfr[4][2];
        #pragma unroll
        for (int i = 0; i < 4; ++i)
            #pragma unroll
            for (int ks = 0; ks < 2; ++ks) {
                af[i][ks]  = *(const bf16x8*)&Xs[(wr*64 + i*16 + lm)*72 + ks*32 + lg*8];
                bfr[i][ks] = *(const bf16x8*)&Ws[(wc*64 + i*16 + lm)*72 + ks*32 + lg*8];
            }
        #pragma unroll
        for (int i = 0; i < 4; ++i)
            #pragma unroll
            for (int j = 0; j < 4; ++j) {
                acc[i][j] = __builtin_amdgcn_mfma_f32_16x16x32_bf16(af[i][0], bfr[j][0], acc[i][j], 0, 0, 0);
                acc[i][j] = __builtin_amdgcn_mfma_f32_16x16x32_bf16(af[i][1], bfr[j][1], acc[i][j], 0, 0, 0);
            }
    }

    // ---- epilogue: direct stores + inline stats ----
    float s4[4] = {}, q4[4] = {};
    #pragma unroll
    for (int j = 0; j < 4; ++j) {
        int col = c0 + wc*64 + j*16 + lm;
        float bj = bias[col];
        #pragma unroll
        for (int i = 0; i < 4; ++i) {
            #pragma unroll
            for (int r = 0; r < 4; ++r) {
                int row = r0 + wr*64 + i*16 + lg*4 + r;
                size_t off = (size_t)row * M + col;
                float v = acc[i][j][r] + bj;
                if (RELU) v = fmaxf(v, 0.f);
                if (SCALEQ) { if (col < 256) v *= 0.17677669529663687f; }
                if (ADDB) v += bf2f(addb[off]);
                if (STATS) { s4[j] += v; q4[j] = fmaf(v, v, q4[j]); }
                Y[off] = f2bf(v);
            }
        }
    }
    if (STATS) {
        #pragma unroll
        for (int j = 0; j < 4; ++j) {
            s4[j] += __shfl_xor(s4[j], 16); q4[j] += __shfl_xor(q4[j], 16);
            s4[j] += __shfl_xor(s4[j], 32); q4[j] += __shfl_xor(q4[j], 32);
        }
        if (lg == 0) {
            #pragma unroll
            for (int j = 0; j < 4; ++j) {
                int col = c0 + wc*64 + j*16 + lm;
                atomicAdd(&st[col], s4[j]);
                atomicAdd(&st[256 + col], q4[j]);
            }
        }
    }
}

// ---------------------------------------------------------------------------
// MFMA bf16 attention body (R11/NQT=4-verified). SM >= 23296 shorts.
// ---------------------------------------------------------------------------
__device__ __forceinline__ void attn_body(
    int aid, const short* __restrict__ QKV, short* __restrict__ O, short* SM)
{
    const int bh = aid & 255;
    const int qblk = aid >> 8;
    const int b = bh >> 3, h = bh & 7;
    const int t = threadIdx.x, w = t >> 6, l = t & 63;
    const int lg = l >> 4, lm = l & 15;
    const size_t gb = (size_t)b * PG * 768;
    const int q0 = qblk * 256 + w * 64;

    short* Ks = SM;                       // 64*40 = 2560
    short* Vt = SM + 2560;                // 32*72 = 2304
    short* Pw = SM + 4864 + w * 4608;     // per-wave 64*72

    bf16x8 qa[4];
    #pragma unroll
    for (int qt = 0; qt < 4; ++qt)
        qa[qt] = *(const bf16x8*)(QKV + gb + (size_t)(q0 + qt*16 + lm) * 768 + h*32 + lg*8);

    f32x4 acc[4][2];
    #pragma unroll
    for (int qt = 0; qt < 4; ++qt)
        #pragma unroll
        for (int hf = 0; hf < 2; ++hf)
            acc[qt][hf] = (f32x4){0.f, 0.f, 0.f, 0.f};
    float lsum[4] = {0.f, 0.f, 0.f, 0.f};

    const int srow = t >> 2;
    const int sq = (t & 3) * 8;
    const short* Kb = QKV + gb + 256 + h*32 + sq;
    const short* Vb = QKV + gb + 512 + h*32 + sq;

    bf16x8 kreg = *(const bf16x8*)(Kb + (size_t)srow * 768);
    bf16x8 vreg = *(const bf16x8*)(Vb + (size_t)srow * 768);

    for (int kt = 0; kt < 16; ++kt) {
        *(bf16x8*)&Ks[srow * 40 + sq] = kreg;
        #pragma unroll
        for (int j = 0; j < 8; ++j) Vt[(sq + j) * 72 + srow] = vreg[j];
        __syncthreads();
        if (kt < 15) {
            kreg = *(const bf16x8*)(Kb + (size_t)((kt + 1) * 64 + srow) * 768);
            vreg = *(const bf16x8*)(Vb + (size_t)((kt + 1) * 64 + srow) * 768);
        }

        bf16x8 kf[4];
        #pragma unroll
        for (int s = 0; s < 4; ++s)
            kf[s] = *(const bf16x8*)&Ks[(s*16 + lm) * 40 + lg*8];

        #pragma unroll
        for (int qt = 0; qt < 4; ++qt) {
            #pragma unroll
            for (int s = 0; s < 4; ++s) {
                f32x4 c = (f32x4){0.f, 0.f, 0.f, 0.f};
                c = __builtin_amdgcn_mfma_f32_16x16x32_bf16(kf[s], qa[qt], c, 0, 0, 0);
                float p0 = __expf(c[0]), p1 = __expf(c[1]);
                float p2 = __expf(c[2]), p3 = __expf(c[3]);
                lsum[qt] += (p0 + p1) + (p2 + p3);
                short4 pk;
                pk.x = f2bf(p0); pk.y = f2bf(p1); pk.z = f2bf(p2); pk.w = f2bf(p3);
                *(short4*)&Pw[(qt*16 + lm) * 72 + s*16 + lg*4] = pk;
            }
        }

        bf16x8 vf[2][2];
        #pragma unroll
        for (int hf = 0; hf < 2; ++hf)
            #pragma unroll
            for (int g = 0; g < 2; ++g)
                vf[hf][g] = *(const bf16x8*)&Vt[(hf*16 + lm) * 72 + g*32 + lg*8];
        #pragma unroll
        for (int qt = 0; qt < 4; ++qt) {
            #pragma unroll
            for (int g = 0; g < 2; ++g) {
                bf16x8 pf = *(const bf16x8*)&Pw[(qt*16 + lm) * 72 + g*32 + lg*8];
                #pragma unroll
                for (int hf = 0; hf < 2; ++hf)
                    acc[qt][hf] = __builtin_amdgcn_mfma_f32_16x16x32_bf16(
                        pf, vf[hf][g], acc[qt][hf], 0, 0, 0);
            }
        }
        __syncthreads();
    }

    float red[4];
    #pragma unroll
    for (int qt = 0; qt < 4; ++qt) {
        float v = lsum[qt];
        v += __shfl_xor(v, 16);
        v += __shfl_xor(v, 32);
        red[qt] = 1.0f / v;
    }
    #pragma unroll
    for (int qt = 0; qt < 4; ++qt) {
        #pragma unroll
        for (int r = 0; r < 4; ++r) {
            float inv = __shfl(red[qt], lg*4 + r);
            int qrow = q0 + qt*16 + lg*4 + r;
            short* Op = O + ((size_t)b * PG + qrow) * D + h * 32;
            Op[lm]      = f2bf(acc[qt][0][r] * inv);
            Op[16 + lm] = f2bf(acc[qt][1][r] * inv);
        }
    }
}

// ===========================================================================
// fused launches
// ===========================================================================
// gin1 (512) || qkv (1536): 2048 blocks = exactly 2 residency waves @4/CU
__global__ __launch_bounds__(256) void gemm_ab(
    const short* __restrict__ Zb, const short* __restrict__ gw1b,
    const float* __restrict__ gb1, short* __restrict__ T1b,
    const short* __restrict__ xb, const short* __restrict__ inwb,
    const float* __restrict__ inb, short* __restrict__ QKVb)
{
    __shared__ __align__(16) short SM[18432];
    int bid = blockIdx.x;
    int grp = bid >> 2, rem = bid & 3;
    if (rem == 0)
        gemm_body<true , false, false, false>(
            grp, 2, 512, Zb, gw1b, gb1, nullptr, T1b, nullptr, 256, 256, SM);
    else
        gemm_body<false, false, false, true >(
            grp * 3 + rem - 1, 6, 1536, xb, inwb, inb, nullptr, QKVb, nullptr, 256, 768, SM);
}

// attn (1024) || gin2 (512): 1536 blocks = exactly 2 residency waves @3/CU;
// gin2 fills attention's tail wave.
__global__ __launch_bounds__(256) void attn_gin2(
    const short* __restrict__ QKVb, short* __restrict__ Ob,
    const short* __restrict__ T1b, const short* __restrict__ gw2b,
    const float* __restrict__ gb2, const short* __restrict__ xb,
    short* __restrict__ F0b, float* __restrict__ st)
{
    __shared__ __align__(16) short SM[23296];
    int bid = blockIdx.x;
    int grp = bid / 3, rem = bid % 3;
    if (rem == 0)
        gemm_body<false, true , true , false>(
            grp, 2, 512, T1b, gw2b, gb2, xb, F0b, st, 256, 256, SM);
    else
        attn_body(grp * 2 + rem - 1, QKVb, Ob, SM);
}

// standalone GEMM
template<bool RELU, bool ADDB, bool STATS, bool SCALEQ>
__global__ __launch_bounds__(256) void gemm_k(
    const short* __restrict__ X, const short* __restrict__ W,
    const float* __restrict__ bias, const short* __restrict__ addb,
    short* __restrict__ Y, float* __restrict__ st, int K, int M, int nbx)
{
    __shared__ __align__(16) short SM[18432];
    gemm_body<RELU, ADDB, STATS, SCALEQ>(
        blockIdx.x, nbx, gridDim.x, X, W, bias, addb, Y, st, K, M, SM);
}

// ---------------------------------------------------------------------------
// Hc = BN(A; gl,bl,st[0:512]) + BN(B; ga,ba,st[512:1024])   (bf16 in/out)
// ---------------------------------------------------------------------------
__global__ __launch_bounds__(256) void bn_combine(
    const short* __restrict__ A, const short* __restrict__ Bq,
    const float* __restrict__ gl, const float* __restrict__ bl,
    const float* __restrict__ ga, const float* __restrict__ ba,
    const float* __restrict__ st, short* __restrict__ H, int n)
{
    const float invN = 1.0f / (float)n;
    size_t i = (size_t)blockIdx.x * 256 + threadIdx.x;
    int c0 = (int)((i & 31) << 3);
    bf16x8 av = ((const bf16x8*)A)[i];
    bf16x8 bv = ((const bf16x8*)Bq)[i];
    bf16x8 o;
    #pragma unroll
    for (int e = 0; e < 8; ++e) {
        int c = c0 + e;
        float m1 = st[c] * invN;
        float v1 = fmaxf(st[256 + c] * invN - m1 * m1, 0.f);
        float m2 = st[512 + c] * invN;
        float v2 = fmaxf(st[768 + c] * invN - m2 * m2, 0.f);
        float y1 = gl[c] * (bf2f(av[e]) - m1) * rsqrtf(v1 + 1e-5f) + bl[c];
        float y2 = ga[c] * (bf2f(bv[e]) - m2) * rsqrtf(v2 + 1e-5f) + ba[c];
        o[e] = f2bf(y1 + y2);
    }
    ((bf16x8*)H)[i] = o;
}

// ---------------------------------------------------------------------------
// out(f32) = BN(X bf16; g,b,st)
// ---------------------------------------------------------------------------
__global__ __launch_bounds__(256) void bn_apply(
    const short* __restrict__ X, const float* __restrict__ g,
    const float* __restrict__ bb, const float* __restrict__ st,
    float* __restrict__ out, int n)
{
    const float invN = 1.0f / (float)n;
    size_t i = (size_t)blockIdx.x * 256 + threadIdx.x;
    int c0 = (int)((i & 31) << 3);
    bf16x8 xv = ((const bf16x8*)X)[i];
    float r[8];
    #pragma unroll
    for (int e = 0; e < 8; ++e) {
        int c = c0 + e;
        float m = st[c] * invN;
        float v = fmaxf(st[256 + c] * invN - m * m, 0.f);
        r[e] = g[c] * (bf2f(xv[e]) - m) * rsqrtf(v + 1e-5f) + bb[c];
    }
    float4 o0 = {r[0], r[1], r[2], r[3]};
    float4 o1 = {r[4], r[5], r[6], r[7]};
    ((float4*)out)[i * 2]     = o0;
    ((float4*)out)[i * 2 + 1] = o1;
}

// ---------------------------------------------------------------------------
extern "C" void kernel_launch(void* const* d_in, const int* in_sizes, int n_in,
                              void* d_out, int out_size, void* d_ws, size_t ws_size,
                              hipStream_t stream)
{
    const float* x    = (const float*)d_in[0];
    const int*   ei   = (const int*)d_in[1];
    const float* ea   = (const float*)d_in[2];
    const float* gw1  = (const float*)d_in[3];
    const float* gb1  = (const float*)d_in[4];
    const float* gw2  = (const float*)d_in[5];
    const float* gb2  = (const float*)d_in[6];
    const float* inw  = (const float*)d_in[7];
    const float* inb  = (const float*)d_in[8];
    const float* outw = (const float*)d_in[9];
    const float* outb = (const float*)d_in[10];
    const float* g1l  = (const float*)d_in[11];
    const float* b1l  = (const float*)d_in[12];
    const float* g1a  = (const float*)d_in[13];
    const float* b1a  = (const float*)d_in[14];
    const float* fw1  = (const float*)d_in[15];
    const float* fb1  = (const float*)d_in[16];
    const float* fw2  = (const float*)d_in[17];
    const float* fb2  = (const float*)d_in[18];
    const float* g2   = (const float*)d_in[19];
    const float* b2   = (const float*)d_in[20];
    float* out = (float*)d_out;

    const int N = in_sizes[0] / D;   // 32768
    const int E = in_sizes[1] / 2;   // 262144
    const size_t ND = (size_t)N * D;

    // ---- workspace: 7 bf16 N*D slots + weights + stats + cnt + bucket ----
    short* Bp = (short*)d_ws;
    short* S0 = Bp;                  // QKV[0] -> F1b
    short* S1 = Bp + ND;             // QKV[1] -> Hcb
    short* S2 = Bp + 2 * ND;         // QKV[2] -> FFHb[0]
    short* S3 = Bp + 3 * ND;         // Zb -> F0b -> FFHb[1]   (S2,S3 contiguous)
    short* S4 = Bp + 4 * ND;         // Ob -> Gb (ff2 out)
    short* S5 = Bp + 5 * ND;         // T1b
    short* xb = Bp + 6 * ND;         // bf16(x), emitted by csr_aggr
    short* Wb = Bp + 7 * ND;         // 655360 shorts of bf16 weights
    short* gw1b = Wb, *gw2b = Wb + 65536, *inwb = Wb + 131072;
    short* outwb = Wb + 327680, *fw1b = Wb + 393216, *fw2b = Wb + 524288;
    float* st = (float*)(Wb + 655360);
    int* cnt = (int*)(st + 1536);        // contiguous with st -> single memset
    int2* bucket = (int2*)(cnt + N);     // N * BSLOT int2

    const int EB = (E + 255) / 256;

    // ---- memset st+cnt, then fused cvt_weights | bucket scatter ----
    hipMemsetAsync(st, 0, (1536 + (size_t)N) * sizeof(int), stream);
    prep_kernel<<<320 + EB, 256, 0, stream>>>(
        gw1, gw2, inw, outw, fw1, fw2, Wb, ei, ei + E, cnt, bucket, E);

    // ---- edge aggregation: Zb(S3) + xb ----
    csr_aggr<<<(N * 64) / 256, 256, 0, stream>>>(x, ea, cnt, bucket, S3, xb);

    // ---- gin1(S3 -> S5) || qkv(xb -> S0..S2, Q pre-scaled) ----
    gemm_ab<<<2048, 256, 0, stream>>>(S3, gw1b, gb1, S5, xb, inwb, inb, S0);

    // ---- attn(S0..S2 -> S4) || gin2(S5 +xb -> S3, stats[0]) ----
    attn_gin2<<<1536, 256, 0, stream>>>(S0, S4, S5, gw2b, gb2, xb, S3, st);

    // ---- outproj: S4 +xb -> S0 (F1b), stats[512] ----
    gemm_k<false, true , true , false><<<512, 256, 0, stream>>>(
        S4, outwb, outb, xb, S0, st + 512, 256, 256, 2);

    // ---- combine + FF (ff2: +Hc, stats[1024]) + final BN ----
    bn_combine<<<(unsigned)(ND / 8 / 256), 256, 0, stream>>>(
        S3, S0, g1l, b1l, g1a, b1a, st, S1, N);
    gemm_k<true , false, false, false><<<1024, 256, 0, stream>>>(
        S1, fw1b, fb1, nullptr, S2, nullptr, 256, 512, 4);
    gemm_k<false, true , true , false><<<512, 256, 0, stream>>>(
        S2, fw2b, fb2, S1, S4, st + 1024, 512, 256, 2);
    bn_apply<<<(unsigned)(ND / 8 / 256), 256, 0, stream>>>(
        S4, g2, b2, st + 1024, out, N);
}

// Round 15
// 337.901 us; speedup vs baseline: 1.0942x; 1.0942x over previous
//
#include <hip/hip_runtime.h>
#include <hip/hip_bf16.h>

constexpr int D = 256;   // dim_h
constexpr int PG = 1024; // nodes per graph
constexpr int BSLOT = 64; // bucket capacity per node (Poisson(8) => never hit)

typedef __attribute__((ext_vector_type(8))) short bf16x8;  // 8 bf16 in 4 VGPRs
typedef __attribute__((ext_vector_type(4))) float f32x4;

__device__ inline short f2bf(float f) {
    __hip_bfloat16 h = __float2bfloat16(f);
    return *reinterpret_cast<short*>(&h);
}
__device__ inline float bf2f(short s) {
    return __uint_as_float(((unsigned)(unsigned short)s) << 16);
}

// ===========================================================================
// prep: weights f32->bf16 (blocks 0..319) | bucket scatter (blocks 320..)
// ===========================================================================
__global__ __launch_bounds__(256) void prep_kernel(
    const float* __restrict__ w1, const float* __restrict__ w2,
    const float* __restrict__ w3, const float* __restrict__ w4,
    const float* __restrict__ w5, const float* __restrict__ w6,
    short* __restrict__ out,
    const int* __restrict__ src, const int* __restrict__ dst,
    int* __restrict__ cnt, int2* __restrict__ bucket, int E)
{
    int bid = blockIdx.x;
    if (bid >= 320) {
        int e = (bid - 320) * 256 + threadIdx.x;
        if (e < E) {
            int d = dst[e];
            int pos = atomicAdd(&cnt[d], 1);
            if (pos < BSLOT) {
                int2 v; v.x = e; v.y = src[e];
                bucket[d * BSLOT + pos] = v;
            }
        }
        return;
    }
    int i = bid * 256 + threadIdx.x;   // [0, 81920)
    const float* sp; int base;
    if (i < 16384)      { if (i < 8192) { sp = w1; base = 0; }
                          else          { sp = w2; base = 8192; } }
    else if (i < 40960) { sp = w3; base = 16384; }
    else if (i < 49152) { sp = w4; base = 40960; }
    else if (i < 65536) { sp = w5; base = 49152; }
    else                { sp = w6; base = 65536; }
    int k = i - base;
    float4 a = ((const float4*)sp)[k * 2];
    float4 b = ((const float4*)sp)[k * 2 + 1];
    bf16x8 v;
    v[0] = f2bf(a.x); v[1] = f2bf(a.y); v[2] = f2bf(a.z); v[3] = f2bf(a.w);
    v[4] = f2bf(b.x); v[5] = f2bf(b.y); v[6] = f2bf(b.z); v[7] = f2bf(b.w);
    ((bf16x8*)out)[i] = v;
}

// ===========================================================================
// bucket aggregation -> bf16 Z, also emits xb = bf16(x). One wave per node.
// ===========================================================================
__global__ __launch_bounds__(256) void csr_aggr(
    const float* __restrict__ x, const float* __restrict__ ea,
    const int* __restrict__ cnt, const int2* __restrict__ bucket,
    short* __restrict__ z, short* __restrict__ xb)
{
    int gid = blockIdx.x * 256 + threadIdx.x;
    int node = gid >> 6;
    int c = (gid & 63) << 2;
    int deg = cnt[node];
    if (deg > BSLOT) deg = BSLOT;
    const int2* bk = bucket + (size_t)node * BSLOT;
    float4 xv = *(const float4*)(x + (size_t)node * D + c);
    short4 xr;
    xr.x = f2bf(xv.x); xr.y = f2bf(xv.y); xr.z = f2bf(xv.z); xr.w = f2bf(xv.w);
    *(short4*)(xb + (size_t)node * D + c) = xr;
    float4 acc = xv;
    for (int i = 0; i < deg; ++i) {
        int2 es = bk[i];
        float4 xa = *(const float4*)(x + (size_t)es.y * D + c);
        float4 av = *(const float4*)(ea + (size_t)es.x * D + c);
        acc.x += fmaxf(xa.x + av.x, 0.f);
        acc.y += fmaxf(xa.y + av.y, 0.f);
        acc.z += fmaxf(xa.z + av.z, 0.f);
        acc.w += fmaxf(xa.w + av.w, 0.f);
    }
    short4 r;
    r.x = f2bf(acc.x); r.y = f2bf(acc.y); r.z = f2bf(acc.z); r.w = f2bf(acc.w);
    *(short4*)(z + (size_t)node * D + c) = r;
}

// ===========================================================================
// MFMA bf16 GEMM body (R7/R13-proven). SM >= 18432 shorts.
// ===========================================================================
template<bool RELU, bool ADDB, bool STATS, bool SCALEQ>
__device__ __forceinline__ void gemm_body(
    int bid, int nbx, int nwg,
    const short* __restrict__ X, const short* __restrict__ W,
    const float* __restrict__ bias, const short* __restrict__ addb,
    short* __restrict__ Y, float* __restrict__ st, int K, int M,
    short* SM)
{
    short* Xs = SM;            // 128*72
    short* Ws = SM + 9216;     // 128*72

    const int cpx = nwg >> 3;                     // nwg % 8 == 0 always
    const int wg  = (bid & 7) * cpx + (bid >> 3);
    const int r0 = (wg / nbx) * 128;
    const int c0 = (wg % nbx) * 128;

    const int t = threadIdx.x, w = t >> 6, l = t & 63;
    const int wr = w >> 1, wc = w & 1, lg = l >> 4, lm = l & 15;
    const int srow = t >> 3;            // staging row 0..31
    const int scol = (t & 7) * 8;       // staging col 0..56

    f32x4 acc[4][4];
    #pragma unroll
    for (int i = 0; i < 4; ++i)
        #pragma unroll
        for (int j = 0; j < 4; ++j)
            acc[i][j] = (f32x4){0.f, 0.f, 0.f, 0.f};

    for (int k0 = 0; k0 < K; k0 += 64) {
        __syncthreads();
        #pragma unroll
        for (int it = 0; it < 4; ++it) {
            int r = it * 32 + srow;
            bf16x8 xv = *(const bf16x8*)(X + (size_t)(r0 + r) * K + k0 + scol);
            bf16x8 wv = *(const bf16x8*)(W + (size_t)(c0 + r) * K + k0 + scol);
            *(bf16x8*)&Xs[r * 72 + scol] = xv;
            *(bf16x8*)&Ws[r * 72 + scol] = wv;
        }
        __syncthreads();

        bf16x8 af[4][2], bfr[4][2];
        #pragma unroll
        for (int i = 0; i < 4; ++i)
            #pragma unroll
            for (int ks = 0; ks < 2; ++ks) {
                af[i][ks]  = *(const bf16x8*)&Xs[(wr*64 + i*16 + lm)*72 + ks*32 + lg*8];
                bfr[i][ks] = *(const bf16x8*)&Ws[(wc*64 + i*16 + lm)*72 + ks*32 + lg*8];
            }
        #pragma unroll
        for (int i = 0; i < 4; ++i)
            #pragma unroll
            for (int j = 0; j < 4; ++j) {
                acc[i][j] = __builtin_amdgcn_mfma_f32_16x16x32_bf16(af[i][0], bfr[j][0], acc[i][j], 0, 0, 0);
                acc[i][j] = __builtin_amdgcn_mfma_f32_16x16x32_bf16(af[i][1], bfr[j][1], acc[i][j], 0, 0, 0);
            }
    }

    // ---- epilogue: direct stores + inline stats ----
    float s4[4] = {}, q4[4] = {};
    #pragma unroll
    for (int j = 0; j < 4; ++j) {
        int col = c0 + wc*64 + j*16 + lm;
        float bj = bias[col];
        #pragma unroll
        for (int i = 0; i < 4; ++i) {
            #pragma unroll
            for (int r = 0; r < 4; ++r) {
                int row = r0 + wr*64 + i*16 + lg*4 + r;
                size_t off = (size_t)row * M + col;
                float v = acc[i][j][r] + bj;
                if (RELU) v = fmaxf(v, 0.f);
                if (SCALEQ) { if (col < 256) v *= 0.17677669529663687f; }
                if (ADDB) v += bf2f(addb[off]);
                if (STATS) { s4[j] += v; q4[j] = fmaf(v, v, q4[j]); }
                Y[off] = f2bf(v);
            }
        }
    }
    if (STATS) {
        #pragma unroll
        for (int j = 0; j < 4; ++j) {
            s4[j] += __shfl_xor(s4[j], 16); q4[j] += __shfl_xor(q4[j], 16);
            s4[j] += __shfl_xor(s4[j], 32); q4[j] += __shfl_xor(q4[j], 32);
        }
        if (lg == 0) {
            #pragma unroll
            for (int j = 0; j < 4; ++j) {
                int col = c0 + wc*64 + j*16 + lm;
                atomicAdd(&st[col], s4[j]);
                atomicAdd(&st[256 + col], q4[j]);
            }
        }
    }
}

// standalone GEMM
template<bool RELU, bool ADDB, bool STATS, bool SCALEQ>
__global__ __launch_bounds__(256) void gemm_k(
    const short* __restrict__ X, const short* __restrict__ W,
    const float* __restrict__ bias, const short* __restrict__ addb,
    short* __restrict__ Y, float* __restrict__ st, int K, int M, int nbx)
{
    __shared__ __align__(16) short SM[18432];
    gemm_body<RELU, ADDB, STATS, SCALEQ>(
        blockIdx.x, nbx, gridDim.x, X, W, bias, addb, Y, st, K, M, SM);
}

// gin2 || outproj: two independent, identically-shaped 256->256 GEMMs
// (same body, same LDS, same occupancy) in one launch, parity-split.
__global__ __launch_bounds__(256) void gemm_dual(
    const short* __restrict__ X1, const short* __restrict__ W1,
    const float* __restrict__ b1, const short* __restrict__ add1,
    short* __restrict__ Y1, float* __restrict__ st1,
    const short* __restrict__ X2, const short* __restrict__ W2,
    const float* __restrict__ b2, const short* __restrict__ add2,
    short* __restrict__ Y2, float* __restrict__ st2)
{
    __shared__ __align__(16) short SM[18432];
    int bid = blockIdx.x;
    if (bid & 1)
        gemm_body<false, true, true, false>(
            bid >> 1, 2, 512, X2, W2, b2, add2, Y2, st2, 256, 256, SM);
    else
        gemm_body<false, true, true, false>(
            bid >> 1, 2, 512, X1, W1, b1, add1, Y1, st1, 256, 256, SM);
}

// ===========================================================================
// MFMA bf16 attention (NQT=4, qt-half P-tile): each wave owns 64 q-rows but
// processes qt-pairs through a HALF-size wave-private P tile (32x72) -> LDS
// 28.2KB -> 4 blocks/CU -> all 1024 blocks co-resident (no tail wave).
// No extra barrier: P is wave-private, within-wave ds ordering via lgkmcnt.
// ===========================================================================
__global__ __launch_bounds__(256) void attn_mfma(
    const short* __restrict__ QKV, short* __restrict__ O)
{
    const int bh = blockIdx.x & 255;
    const int qblk = blockIdx.x >> 8;
    const int b = bh >> 3, h = bh & 7;
    const int t = threadIdx.x, w = t >> 6, l = t & 63;
    const int lg = l >> 4, lm = l & 15;
    const size_t gb = (size_t)b * PG * 768;
    const int q0 = qblk * 256 + w * 64;

    __shared__ __align__(16) short Ks[64 * 40];       // 2560
    __shared__ __align__(16) short Vt[32 * 72];       // 2304
    __shared__ __align__(16) short Ps[4][32 * 72];    // 4 * 2304 (half-size)

    bf16x8 qa[4];
    #pragma unroll
    for (int qt = 0; qt < 4; ++qt)
        qa[qt] = *(const bf16x8*)(QKV + gb + (size_t)(q0 + qt*16 + lm) * 768 + h*32 + lg*8);

    f32x4 acc[4][2];
    #pragma unroll
    for (int qt = 0; qt < 4; ++qt)
        #pragma unroll
        for (int hf = 0; hf < 2; ++hf)
            acc[qt][hf] = (f32x4){0.f, 0.f, 0.f, 0.f};
    float lsum[4] = {0.f, 0.f, 0.f, 0.f};

    const int srow = t >> 2;
    const int sq = (t & 3) * 8;
    const short* Kb = QKV + gb + 256 + h*32 + sq;
    const short* Vb = QKV + gb + 512 + h*32 + sq;

    bf16x8 kreg = *(const bf16x8*)(Kb + (size_t)srow * 768);
    bf16x8 vreg = *(const bf16x8*)(Vb + (size_t)srow * 768);

    for (int kt = 0; kt < 16; ++kt) {
        *(bf16x8*)&Ks[srow * 40 + sq] = kreg;
        #pragma unroll
        for (int j = 0; j < 8; ++j) Vt[(sq + j) * 72 + srow] = vreg[j];
        __syncthreads();
        if (kt < 15) {
            kreg = *(const bf16x8*)(Kb + (size_t)((kt + 1) * 64 + srow) * 768);
            vreg = *(const bf16x8*)(Vb + (size_t)((kt + 1) * 64 + srow) * 768);
        }

        bf16x8 kf[4];
        #pragma unroll
        for (int s = 0; s < 4; ++s)
            kf[s] = *(const bf16x8*)&Ks[(s*16 + lm) * 40 + lg*8];

        bf16x8 vf[2][2];
        #pragma unroll
        for (int hf = 0; hf < 2; ++hf)
            #pragma unroll
            for (int g = 0; g < 2; ++g)
                vf[hf][g] = *(const bf16x8*)&Vt[(hf*16 + lm) * 72 + g*32 + lg*8];

        #pragma unroll
        for (int h2 = 0; h2 < 2; ++h2) {
            // ---- QK^T (swapped) + exp -> half P tile (rows qi*16+lm) ----
            #pragma unroll
            for (int qi = 0; qi < 2; ++qi) {
                const int qt = h2 * 2 + qi;
                #pragma unroll
                for (int s = 0; s < 4; ++s) {
                    f32x4 c = (f32x4){0.f, 0.f, 0.f, 0.f};
                    c = __builtin_amdgcn_mfma_f32_16x16x32_bf16(kf[s], qa[qt], c, 0, 0, 0);
                    float p0 = __expf(c[0]), p1 = __expf(c[1]);
                    float p2 = __expf(c[2]), p3 = __expf(c[3]);
                    lsum[qt] += (p0 + p1) + (p2 + p3);
                    short4 pk;
                    pk.x = f2bf(p0); pk.y = f2bf(p1); pk.z = f2bf(p2); pk.w = f2bf(p3);
                    *(short4*)&Ps[w][(qi*16 + lm) * 72 + s*16 + lg*4] = pk;
                }
            }
            // ---- PV for this qt-pair ----
            #pragma unroll
            for (int qi = 0; qi < 2; ++qi) {
                const int qt = h2 * 2 + qi;
                #pragma unroll
                for (int g = 0; g < 2; ++g) {
                    bf16x8 pf = *(const bf16x8*)&Ps[w][(qi*16 + lm) * 72 + g*32 + lg*8];
                    #pragma unroll
                    for (int hf = 0; hf < 2; ++hf)
                        acc[qt][hf] = __builtin_amdgcn_mfma_f32_16x16x32_bf16(
                            pf, vf[hf][g], acc[qt][hf], 0, 0, 0);
                }
            }
        }
        __syncthreads();
    }

    float red[4];
    #pragma unroll
    for (int qt = 0; qt < 4; ++qt) {
        float v = lsum[qt];
        v += __shfl_xor(v, 16);
        v += __shfl_xor(v, 32);
        red[qt] = 1.0f / v;        // valid for q = qt*16 + lm
    }
    #pragma unroll
    for (int qt = 0; qt < 4; ++qt) {
        #pragma unroll
        for (int r = 0; r < 4; ++r) {
            float inv = __shfl(red[qt], lg*4 + r);
            int qrow = q0 + qt*16 + lg*4 + r;
            short* Op = O + ((size_t)b * PG + qrow) * D + h * 32;
            Op[lm]      = f2bf(acc[qt][0][r] * inv);
            Op[16 + lm] = f2bf(acc[qt][1][r] * inv);
        }
    }
}

// ---------------------------------------------------------------------------
// Hc = BN(A; gl,bl,st[0:512]) + BN(B; ga,ba,st[512:1024])   (bf16 in/out)
// ---------------------------------------------------------------------------
__global__ __launch_bounds__(256) void bn_combine(
    const short* __restrict__ A, const short* __restrict__ Bq,
    const float* __restrict__ gl, const float* __restrict__ bl,
    const float* __restrict__ ga, const float* __restrict__ ba,
    const float* __restrict__ st, short* __restrict__ H, int n)
{
    const float invN = 1.0f / (float)n;
    size_t i = (size_t)blockIdx.x * 256 + threadIdx.x;
    int c0 = (int)((i & 31) << 3);
    bf16x8 av = ((const bf16x8*)A)[i];
    bf16x8 bv = ((const bf16x8*)Bq)[i];
    bf16x8 o;
    #pragma unroll
    for (int e = 0; e < 8; ++e) {
        int c = c0 + e;
        float m1 = st[c] * invN;
        float v1 = fmaxf(st[256 + c] * invN - m1 * m1, 0.f);
        float m2 = st[512 + c] * invN;
        float v2 = fmaxf(st[768 + c] * invN - m2 * m2, 0.f);
        float y1 = gl[c] * (bf2f(av[e]) - m1) * rsqrtf(v1 + 1e-5f) + bl[c];
        float y2 = ga[c] * (bf2f(bv[e]) - m2) * rsqrtf(v2 + 1e-5f) + ba[c];
        o[e] = f2bf(y1 + y2);
    }
    ((bf16x8*)H)[i] = o;
}

// ---------------------------------------------------------------------------
// out(f32) = BN(X bf16; g,b,st)
// ---------------------------------------------------------------------------
__global__ __launch_bounds__(256) void bn_apply(
    const short* __restrict__ X, const float* __restrict__ g,
    const float* __restrict__ bb, const float* __restrict__ st,
    float* __restrict__ out, int n)
{
    const float invN = 1.0f / (float)n;
    size_t i = (size_t)blockIdx.x * 256 + threadIdx.x;
    int c0 = (int)((i & 31) << 3);
    bf16x8 xv = ((const bf16x8*)X)[i];
    float r[8];
    #pragma unroll
    for (int e = 0; e < 8; ++e) {
        int c = c0 + e;
        float m = st[c] * invN;
        float v = fmaxf(st[256 + c] * invN - m * m, 0.f);
        r[e] = g[c] * (bf2f(xv[e]) - m) * rsqrtf(v + 1e-5f) + bb[c];
    }
    float4 o0 = {r[0], r[1], r[2], r[3]};
    float4 o1 = {r[4], r[5], r[6], r[7]};
    ((float4*)out)[i * 2]     = o0;
    ((float4*)out)[i * 2 + 1] = o1;
}

// ---------------------------------------------------------------------------
extern "C" void kernel_launch(void* const* d_in, const int* in_sizes, int n_in,
                              void* d_out, int out_size, void* d_ws, size_t ws_size,
                              hipStream_t stream)
{
    const float* x    = (const float*)d_in[0];
    const int*   ei   = (const int*)d_in[1];
    const float* ea   = (const float*)d_in[2];
    const float* gw1  = (const float*)d_in[3];
    const float* gb1  = (const float*)d_in[4];
    const float* gw2  = (const float*)d_in[5];
    const float* gb2  = (const float*)d_in[6];
    const float* inw  = (const float*)d_in[7];
    const float* inb  = (const float*)d_in[8];
    const float* outw = (const float*)d_in[9];
    const float* outb = (const float*)d_in[10];
    const float* g1l  = (const float*)d_in[11];
    const float* b1l  = (const float*)d_in[12];
    const float* g1a  = (const float*)d_in[13];
    const float* b1a  = (const float*)d_in[14];
    const float* fw1  = (const float*)d_in[15];
    const float* fb1  = (const float*)d_in[16];
    const float* fw2  = (const float*)d_in[17];
    const float* fb2  = (const float*)d_in[18];
    const float* g2   = (const float*)d_in[19];
    const float* b2   = (const float*)d_in[20];
    float* out = (float*)d_out;

    const int N = in_sizes[0] / D;   // 32768
    const int E = in_sizes[1] / 2;   // 262144
    const size_t ND = (size_t)N * D;

    // ---- workspace: 7 bf16 N*D slots + weights + stats + cnt + bucket ----
    short* Bp = (short*)d_ws;
    short* S0 = Bp;                  // Zb -> QKV[0] -> F1b
    short* S1 = Bp + ND;             // QKV[1] -> Hcb
    short* S2 = Bp + 2 * ND;         // QKV[2] -> FFHb[0]
    short* S3 = Bp + 3 * ND;         // F0b -> FFHb[1]   (S2,S3 contiguous)
    short* S4 = Bp + 4 * ND;         // Ob -> Gb (ff2 out)
    short* S5 = Bp + 5 * ND;         // T1b (lives until dual)
    short* xb = Bp + 6 * ND;         // bf16(x), emitted by csr_aggr
    short* Wb = Bp + 7 * ND;         // 655360 shorts of bf16 weights
    short* gw1b = Wb, *gw2b = Wb + 65536, *inwb = Wb + 131072;
    short* outwb = Wb + 327680, *fw1b = Wb + 393216, *fw2b = Wb + 524288;
    float* st = (float*)(Wb + 655360);
    int* cnt = (int*)(st + 1536);        // contiguous with st -> single memset
    int2* bucket = (int2*)(cnt + N);     // N * BSLOT int2

    const int EB = (E + 255) / 256;

    // ---- memset st+cnt, then fused cvt_weights | bucket scatter ----
    hipMemsetAsync(st, 0, (1536 + (size_t)N) * sizeof(int), stream);
    prep_kernel<<<320 + EB, 256, 0, stream>>>(
        gw1, gw2, inw, outw, fw1, fw2, Wb, ei, ei + E, cnt, bucket, E);

    // ---- edge aggregation: Zb(S0) + xb ----
    csr_aggr<<<(N * 64) / 256, 256, 0, stream>>>(x, ea, cnt, bucket, S0, xb);

    // ---- gin1: S0 -> S5 ----
    gemm_k<true , false, false, false><<<512, 256, 0, stream>>>(
        S0, gw1b, gb1, nullptr, S5, nullptr, 256, 256, 2);

    // ---- qkv (bf16 xb, Q pre-scaled): xb -> S0..S2 ----
    gemm_k<false, false, false, true ><<<1536, 256, 0, stream>>>(
        xb, inwb, inb, nullptr, S0, nullptr, 256, 768, 6);

    // ---- attention: S0..S2 -> S4 ----
    attn_mfma<<<(N / PG) * 8 * 4, 256, 0, stream>>>(S0, S4);

    // ---- gin2(S5 +xb, stats[0]) || outproj(S4 +xb, stats[512]) ----
    gemm_dual<<<1024, 256, 0, stream>>>(
        S5, gw2b, gb2, xb, S3, st,
        S4, outwb, outb, xb, S0, st + 512);

    // ---- combine + FF (ff2: +Hc, stats[1024]) + final BN ----
    bn_combine<<<(unsigned)(ND / 8 / 256), 256, 0, stream>>>(
        S3, S0, g1l, b1l, g1a, b1a, st, S1, N);
    gemm_k<true , false, false, false><<<1024, 256, 0, stream>>>(
        S1, fw1b, fb1, nullptr, S2, nullptr, 256, 512, 4);
    gemm_k<false, true , true , false><<<512, 256, 0, stream>>>(
        S2, fw2b, fb2, S1, S4, st + 1024, 512, 256, 2);
    bn_apply<<<(unsigned)(ND / 8 / 256), 256, 0, stream>>>(
        S4, g2, b2, st + 1024, out, N);
}